// Round 9
// baseline (756.678 us; speedup 1.0000x reference)
//
#include <hip/hip_runtime.h>
#include <hip/hip_bf16.h>
#include <stdint.h>

typedef __attribute__((ext_vector_type(8))) short bf16x8;
typedef __attribute__((ext_vector_type(4))) float f32x4;
typedef __attribute__((ext_vector_type(4))) int i32x4;

constexpr int Mdim = 8192;
constexpr int Ndim = 11008;
constexpr int Kdim = 4096;
constexpr int NT = Kdim / 64;            // 64 K-tiles of BK=64

__device__ __forceinline__ unsigned short f2bf(float f) {
    __bf16 h = (__bf16)f;
    return __builtin_bit_cast(unsigned short, h);
}

__device__ __forceinline__ void gload16(const unsigned short* g, unsigned short* lds) {
    __builtin_amdgcn_global_load_lds(
        (const __attribute__((address_space(1))) unsigned int*)g,
        (__attribute__((address_space(3))) unsigned int*)lds,
        16, 0, 0);
}

// ---------------- prepass 1: A fp32 -> bf16 ----------------
__global__ __launch_bounds__(256) void cvtA_kernel(const float* __restrict__ A,
                                                   unsigned short* __restrict__ Ab)
{
    const size_t total8 = (size_t)Mdim * Kdim / 8;
    for (size_t i = (size_t)blockIdx.x * blockDim.x + threadIdx.x; i < total8;
         i += (size_t)gridDim.x * blockDim.x) {
        const float* src = A + i * 8;
        const f32x4 x0 = *(const f32x4*)src;
        const f32x4 x1 = *(const f32x4*)(src + 4);
        union { bf16x8 v; unsigned short u[8]; } h;
        h.u[0] = f2bf(x0[0]); h.u[1] = f2bf(x0[1]);
        h.u[2] = f2bf(x0[2]); h.u[3] = f2bf(x0[3]);
        h.u[4] = f2bf(x1[0]); h.u[5] = f2bf(x1[1]);
        h.u[6] = f2bf(x1[2]); h.u[7] = f2bf(x1[3]);
        *(bf16x8*)(Ab + i * 8) = h.v;
    }
}

// ---------------- prepass 2: W int4 -> dequant bf16, transposed to [N][K] ----------------
__global__ __launch_bounds__(256) void deqW_kernel(const int* __restrict__ Wq,
                                                   const float* __restrict__ Ws,
                                                   unsigned short* __restrict__ Wt)
{
    __shared__ unsigned short T[64][72];
    const int kt = blockIdx.x % (Kdim / 64);
    const int nt = blockIdx.x / (Kdim / 64);
    const int k0 = kt * 64, n0 = nt * 64;
    const int t = threadIdx.x;

    const int pr   = t >> 3;
    const int nloc = (t & 7) * 8;
    const int* wp = Wq + (size_t)(k0 / 2 + pr) * Ndim + n0 + nloc;
    const i32x4 ra = *(const i32x4*)wp;
    const i32x4 rb = *(const i32x4*)(wp + 4);
    const int g = (k0 + 2 * pr) >> 5;
    const float* sp = Ws + (size_t)g * Ndim + n0 + nloc;
    const f32x4 s0 = *(const f32x4*)sp;
    const f32x4 s1 = *(const f32x4*)(sp + 4);
#pragma unroll
    for (int i = 0; i < 8; ++i) {
        const int v = (i < 4) ? ra[i] : rb[i - 4];
        const float s = (i < 4) ? s0[i] : s1[i - 4];
        union { unsigned int w; unsigned short u[2]; } o;
        o.u[0] = f2bf((float)((v & 15) - 8) * s);
        o.u[1] = f2bf((float)(((v >> 4) & 15) - 8) * s);
        *(unsigned int*)&T[nloc + i][2 * pr] = o.w;
    }
    __syncthreads();
    const int nl = t >> 2;
    const int ko = (t & 3) * 16;
    bf16x8 o0 = *(const bf16x8*)&T[nl][ko];
    bf16x8 o1 = *(const bf16x8*)&T[nl][ko + 8];
    unsigned short* dst = Wt + (size_t)(n0 + nl) * Kdim + k0 + ko;
    *(bf16x8*)dst = o0;
    *(bf16x8*)(dst + 8) = o1;
}

// ---- main GEMM: 256x256x64, 8 waves, explicit SW-pipelined reads, 2 barriers/K-tile ----
__global__ __launch_bounds__(512, 2) void gemm256_kernel(
    const unsigned short* __restrict__ Ab,
    const unsigned short* __restrict__ Bt,
    const float* __restrict__ Bias,
    float* __restrict__ Out)
{
    // LDS: A region 4 slots (par,half) of 128x64 bf16, then B region 4 slots. 128 KiB.
    __shared__ unsigned short sh[65536];

    const int tid  = threadIdx.x;
    const int lane = tid & 63;
    const int wid  = tid >> 6;
    const int wr   = wid >> 2;               // 0..1 : M 128-row half
    const int wc   = wid & 3;                // 0..3 : N 64-col quarter
    const int l15  = lane & 15;
    const int l4   = lane >> 4;
    const int swz  = (l15 & 7) << 3;
    const int kb0  = l4 * 8;
    const int kb1  = 32 + l4 * 8;

    // XCD-aware bijective swizzle (1376 % 8 == 0), bm-major chunks per XCD
    const int nwg = (Mdim / 256) * (Ndim / 256);   // 1376
    const int cpx = nwg / 8;                        // 172
    const int wg  = ((int)blockIdx.x % 8) * cpx + (int)blockIdx.x / 8;
    const int nbn = Ndim / 256;                     // 43
    const int bm = wg / nbn, bn = wg % nbn;
    const int m0 = bm * 256, n0 = bn * 256;

    // staging per-thread addresses (pre-swizzled source, linear LDS dest)
    const int sr  = tid >> 3;                       // 0..63
    const int scl = ((tid & 7) * 8) ^ ((sr & 7) << 3);
    const int ldo = sr * 64 + (tid & 7) * 8;        // shorts; + j*4096
    const unsigned short* aSrc = Ab + (size_t)(m0 + sr) * Kdim + scl;
    const unsigned short* bSrc = Bt + (size_t)(n0 + sr) * Kdim + scl;

    auto stageA = [&](int tt, int h, int slot) {
        unsigned short* base = &sh[slot * 8192];
#pragma unroll
        for (int j = 0; j < 2; ++j)
            gload16(aSrc + (size_t)(h * 128 + 64 * j) * Kdim + tt * 64, base + ldo + j * 4096);
    };
    auto stageB = [&](int tt, int h, int slot) {
        unsigned short* base = &sh[32768 + slot * 8192];
#pragma unroll
        for (int j = 0; j < 2; ++j)
            gload16(bSrc + (size_t)(h * 128 + 64 * j) * Kdim + tt * 64, base + ldo + j * 4096);
    };

    f32x4 acc[8][4];
#pragma unroll
    for (int i = 0; i < 8; ++i)
#pragma unroll
        for (int j = 0; j < 4; ++j) acc[i][j] = (f32x4){0.f, 0.f, 0.f, 0.f};

    // prologue: tile0 (A0,A1,B0,B1) + tile1 B halves; wait tile0; barrier
    stageA(0, 0, 0); stageA(0, 1, 1);
    stageB(0, 0, 0); stageB(0, 1, 1);
    stageB(1, 0, 2); stageB(1, 1, 3);
    asm volatile("s_waitcnt vmcnt(4)" ::: "memory");
    __builtin_amdgcn_s_barrier();

    const int browb = (wc & 1) * 64;

    for (int t = 0; t < NT; ++t) {
        const int par = t & 1, parn = par ^ 1;
        const unsigned short* aslot = &sh[(par * 2 + wr) * 8192];
        const unsigned short* bslot = &sh[32768 + (par * 2 + (wc >> 1)) * 8192];

        bf16x8 b[4][2];        // whole-tile B operands
        bf16x8 aP[2][2];       // A quad ping
        bf16x8 aQ[2][2];       // A quad pong

        // ---- tile start: read B (8) + A quad p0 (4) [exposed], A quad p1 (4) [semi] ----
#pragma unroll
        for (int fn = 0; fn < 4; ++fn) {
            const int row = browb + fn * 16 + l15;
            b[fn][0] = *(const bf16x8*)&bslot[row * 64 + (kb0 ^ swz)];
            b[fn][1] = *(const bf16x8*)&bslot[row * 64 + (kb1 ^ swz)];
        }
#pragma unroll
        for (int q = 0; q < 2; ++q) {
            const int row = q * 16 + l15;
            aP[q][0] = *(const bf16x8*)&aslot[row * 64 + (kb0 ^ swz)];
            aP[q][1] = *(const bf16x8*)&aslot[row * 64 + (kb1 ^ swz)];
        }
        if (t + 1 < NT) stageA(t + 1, 0, parn * 2 + 0);
#pragma unroll
        for (int q = 0; q < 2; ++q) {
            const int row = (2 + q) * 16 + l15;
            aQ[q][0] = *(const bf16x8*)&aslot[row * 64 + (kb0 ^ swz)];
            aQ[q][1] = *(const bf16x8*)&aslot[row * 64 + (kb1 ^ swz)];
        }

        // ---- phase 0: MFMA rows 0-31 (aP); waits cover B+aP only ----
        __builtin_amdgcn_s_setprio(1);
#pragma unroll
        for (int ks = 0; ks < 2; ++ks)
#pragma unroll
            for (int q = 0; q < 2; ++q)
#pragma unroll
                for (int fn = 0; fn < 4; ++fn)
                    acc[q][fn] = __builtin_amdgcn_mfma_f32_16x16x32_bf16(
                        aP[q][ks], b[fn][ks], acc[q][fn], 0, 0, 0);
        __builtin_amdgcn_s_setprio(0);

        // ---- read A quad p2 (hides under p0 MFMA just issued) ----
#pragma unroll
        for (int q = 0; q < 2; ++q) {
            const int row = (4 + q) * 16 + l15;
            aP[q][0] = *(const bf16x8*)&aslot[row * 64 + (kb0 ^ swz)];
            aP[q][1] = *(const bf16x8*)&aslot[row * 64 + (kb1 ^ swz)];
        }
        if (t + 1 < NT) stageA(t + 1, 1, parn * 2 + 1);

        // ---- phase 1: MFMA rows 32-63 (aQ) ----
        __builtin_amdgcn_s_setprio(1);
#pragma unroll
        for (int ks = 0; ks < 2; ++ks)
#pragma unroll
            for (int q = 0; q < 2; ++q)
#pragma unroll
                for (int fn = 0; fn < 4; ++fn)
                    acc[2 + q][fn] = __builtin_amdgcn_mfma_f32_16x16x32_bf16(
                        aQ[q][ks], b[fn][ks], acc[2 + q][fn], 0, 0, 0);
        __builtin_amdgcn_s_setprio(0);

        // mid-barrier: all waves finished their B reads (waited before p0 MFMA)
        asm volatile("" ::: "memory");
        __builtin_amdgcn_s_barrier();

        // ---- read A quad p3 (hides under p1 MFMA) ----
#pragma unroll
        for (int q = 0; q < 2; ++q) {
            const int row = (6 + q) * 16 + l15;
            aQ[q][0] = *(const bf16x8*)&aslot[row * 64 + (kb0 ^ swz)];
            aQ[q][1] = *(const bf16x8*)&aslot[row * 64 + (kb1 ^ swz)];
        }

        // ---- phase 2: MFMA rows 64-95 (aP) ----
        __builtin_amdgcn_s_setprio(1);
#pragma unroll
        for (int ks = 0; ks < 2; ++ks)
#pragma unroll
            for (int q = 0; q < 2; ++q)
#pragma unroll
                for (int fn = 0; fn < 4; ++fn)
                    acc[4 + q][fn] = __builtin_amdgcn_mfma_f32_16x16x32_bf16(
                        aP[q][ks], b[fn][ks], acc[4 + q][fn], 0, 0, 0);
        __builtin_amdgcn_s_setprio(0);

        // ---- stage B(t+2) both halves (safe: mid-barrier passed) ----
        if (t + 2 < NT) { stageB(t + 2, 0, par * 2 + 0); stageB(t + 2, 1, par * 2 + 1); }

        // ---- phase 3: MFMA rows 96-127 (aQ) ----
        __builtin_amdgcn_s_setprio(1);
#pragma unroll
        for (int ks = 0; ks < 2; ++ks)
#pragma unroll
            for (int q = 0; q < 2; ++q)
#pragma unroll
                for (int fn = 0; fn < 4; ++fn)
                    acc[6 + q][fn] = __builtin_amdgcn_mfma_f32_16x16x32_bf16(
                        aQ[q][ks], b[fn][ks], acc[6 + q][fn], 0, 0, 0);
        __builtin_amdgcn_s_setprio(0);

        // counted wait: oldest 8 of 12 outstanding = B(t+1)+A(t+1); leave B(t+2) in flight
        if (t < NT - 2)       asm volatile("s_waitcnt vmcnt(4)" ::: "memory");
        else if (t == NT - 2) asm volatile("s_waitcnt vmcnt(0)" ::: "memory");
        asm volatile("" ::: "memory");
        __builtin_amdgcn_s_barrier();   // end-barrier: staged data visible to all
    }

    // ---- epilogue: C/D col = lane&15, row = (lane>>4)*4 + r ----
    const int rb = l4 * 4;
    float bv[4];
#pragma unroll
    for (int fn = 0; fn < 4; ++fn)
        bv[fn] = Bias[n0 + wc * 64 + fn * 16 + l15];
#pragma unroll
    for (int fm = 0; fm < 8; ++fm) {
        const size_t mg = (size_t)(m0 + wr * 128 + fm * 16 + rb);
#pragma unroll
        for (int fn = 0; fn < 4; ++fn) {
            const int ng = n0 + wc * 64 + fn * 16 + l15;
            const float b = bv[fn];
#pragma unroll
            for (int r = 0; r < 4; ++r)
                Out[(mg + r) * Ndim + ng] = acc[fm][fn][r] + b;
        }
    }
}

// ---------------- fallback: fused kernel (if ws too small) ----------------
constexpr int SA = 72;
__global__ __launch_bounds__(256) void w4a32_fused_kernel(
    const float* __restrict__ A,
    const int* __restrict__ Wq,
    const float* __restrict__ Ws,
    const float* __restrict__ Bias,
    float* __restrict__ Out)
{
    __shared__ unsigned short As[128 * SA];
    __shared__ unsigned short Bs[128 * SA];
    const int tid = threadIdx.x;
    const int nbn = Ndim / 128;
    const int bn = blockIdx.x % nbn;
    const int bm = blockIdx.x / nbn;
    const int m0 = bm * 128, n0 = bn * 128;
    const int lane = tid & 63;
    const int wid  = tid >> 6;
    const int wr   = wid >> 1;
    const int wc   = wid & 1;
    const int l15  = lane & 15;
    const int l4   = lane >> 4;
    f32x4 acc[4][4];
#pragma unroll
    for (int i = 0; i < 4; ++i)
#pragma unroll
        for (int j = 0; j < 4; ++j) acc[i][j] = (f32x4){0.f, 0.f, 0.f, 0.f};
    const int a_tr = tid >> 3;
    const int a_tc = (tid & 7) * 8;
    const int kp2  = tid >> 4;
    const int n8   = (tid & 15) * 8;
    for (int kt = 0; kt < Kdim / 64; ++kt) {
        const int k0 = kt * 64;
        __syncthreads();
#pragma unroll
        for (int j = 0; j < 4; ++j) {
            const int ml = a_tr + 32 * j;
            const float* src = A + (size_t)(m0 + ml) * Kdim + (k0 + a_tc);
            const f32x4 x0 = *(const f32x4*)src;
            const f32x4 x1 = *(const f32x4*)(src + 4);
            union { bf16x8 v; unsigned short u[8]; } h;
            h.u[0] = f2bf(x0[0]); h.u[1] = f2bf(x0[1]);
            h.u[2] = f2bf(x0[2]); h.u[3] = f2bf(x0[3]);
            h.u[4] = f2bf(x1[0]); h.u[5] = f2bf(x1[1]);
            h.u[6] = f2bf(x1[2]); h.u[7] = f2bf(x1[3]);
            *(bf16x8*)(&As[ml * SA + (a_tc ^ ((ml & 7) << 3))]) = h.v;
        }
        {
            const int pr = kt * 32 + 2 * kp2;
            const int* wp = Wq + (size_t)pr * Ndim + (n0 + n8);
            const i32x4 r0a = *(const i32x4*)wp;
            const i32x4 r0b = *(const i32x4*)(wp + 4);
            const i32x4 r1a = *(const i32x4*)(wp + Ndim);
            const i32x4 r1b = *(const i32x4*)(wp + Ndim + 4);
            const int g = 2 * kt + (kp2 >> 3);
            const float* sp = Ws + (size_t)g * Ndim + (n0 + n8);
            const f32x4 s0 = *(const f32x4*)sp;
            const f32x4 s1 = *(const f32x4*)(sp + 4);
#pragma unroll
            for (int i = 0; i < 8; ++i) {
                const float s = (i < 4) ? s0[i] : s1[i - 4];
                const int b0 = (i < 4) ? r0a[i] : r0b[i - 4];
                const int b1 = (i < 4) ? r1a[i] : r1b[i - 4];
                union { unsigned long long v; unsigned short u[4]; } o;
                o.u[0] = f2bf((float)((b0 & 15) - 8) * s);
                o.u[1] = f2bf((float)(((b0 >> 4) & 15) - 8) * s);
                o.u[2] = f2bf((float)((b1 & 15) - 8) * s);
                o.u[3] = f2bf((float)(((b1 >> 4) & 15) - 8) * s);
                const int nl = n8 + i;
                const int swzz = ((nl ^ (nl >> 3)) & 7) << 3;
                *(unsigned long long*)(&Bs[nl * SA + ((4 * kp2) ^ swzz)]) = o.v;
            }
        }
        __syncthreads();
#pragma unroll
        for (int ks = 0; ks < 2; ++ks) {
            const int kb  = ks * 32 + l4 * 8;
            const int swa = (l15 & 7) << 3;
            bf16x8 af[4], bfr[4];
#pragma unroll
            for (int fm = 0; fm < 4; ++fm) {
                const int row = wr * 64 + fm * 16 + l15;
                af[fm] = *(const bf16x8*)(&As[row * SA + (kb ^ swa)]);
            }
#pragma unroll
            for (int fn = 0; fn < 4; ++fn) {
                const int nrow = wc * 64 + fn * 16 + l15;
                const int swb = ((nrow ^ (nrow >> 3)) & 7) << 3;
                bfr[fn] = *(const bf16x8*)(&Bs[nrow * SA + (kb ^ swb)]);
            }
#pragma unroll
            for (int fm = 0; fm < 4; ++fm)
#pragma unroll
                for (int fn = 0; fn < 4; ++fn)
                    acc[fm][fn] = __builtin_amdgcn_mfma_f32_16x16x32_bf16(
                        af[fm], bfr[fn], acc[fm][fn], 0, 0, 0);
        }
    }
    const int rb = l4 * 4;
    float bv[4];
#pragma unroll
    for (int fn = 0; fn < 4; ++fn)
        bv[fn] = Bias[n0 + wc * 64 + fn * 16 + l15];
#pragma unroll
    for (int fm = 0; fm < 4; ++fm) {
        const size_t mg = (size_t)(m0 + wr * 64 + fm * 16 + rb);
#pragma unroll
        for (int fn = 0; fn < 4; ++fn) {
            const int ng = n0 + wc * 64 + fn * 16 + l15;
            const float b = bv[fn];
#pragma unroll
            for (int r = 0; r < 4; ++r)
                Out[(mg + r) * Ndim + ng] = acc[fm][fn][r] + b;
        }
    }
}

extern "C" void kernel_launch(void* const* d_in, const int* in_sizes, int n_in,
                              void* d_out, int out_size, void* d_ws, size_t ws_size,
                              hipStream_t stream) {
    const float* A    = (const float*)d_in[0];
    const int* Wq     = (const int*)d_in[1];
    const float* Ws   = (const float*)d_in[2];
    const float* Bias = (const float*)d_in[3];
    float* Out        = (float*)d_out;

    const size_t needA = (size_t)Mdim * Kdim * 2;
    const size_t needW = (size_t)Ndim * Kdim * 2;
    if (ws_size >= needA + needW) {
        unsigned short* Ab = (unsigned short*)d_ws;
        unsigned short* Wt = (unsigned short*)((char*)d_ws + needA);
        cvtA_kernel<<<4096, 256, 0, stream>>>(A, Ab);
        deqW_kernel<<<(Kdim / 64) * (Ndim / 64), 256, 0, stream>>>(Wq, Ws, Wt);
        gemm256_kernel<<<(Mdim / 256) * (Ndim / 256), 512, 0, stream>>>(Ab, Wt, Bias, Out);
    } else {
        w4a32_fused_kernel<<<(Mdim / 128) * (Ndim / 128), 256, 0, stream>>>(A, Wq, Ws, Bias, Out);
    }
}